// Round 10
// baseline (527.019 us; speedup 1.0000x reference)
//
#include <hip/hip_runtime.h>
#include <cstdint>
#include <cstddef>

#define NN 50000
#define NE 800000
#define HD 128
#define GK 16     // chunk-blocks per graph in gpart
#define HNB 64    // edge-slice blocks per (array,half) in deghist
#define SB 128    // stats partial blocks

typedef __attribute__((ext_vector_type(8))) short bf16x8;
typedef __attribute__((ext_vector_type(4))) float f32x4;
typedef _Float16 f16x4 __attribute__((ext_vector_type(4)));
typedef _Float16 f16x8 __attribute__((ext_vector_type(8)));

__device__ inline unsigned short f2bf(float x) {
  unsigned u = __float_as_uint(x);
  u += 0x7FFF + ((u >> 16) & 1);  // round-to-nearest-even
  return (unsigned short)(u >> 16);
}
__device__ inline float bf2f(unsigned short h) { return __uint_as_float((unsigned)h << 16); }

// ---------------- degree histogram via LDS privatization (no global atomics) ----------------
__global__ __launch_bounds__(256) void deghist_kernel(const int* __restrict__ src, const int* __restrict__ dst,
                                                      int* __restrict__ part, int e) {
  __shared__ int hist[25000];  // 100 KB
  const int b = blockIdx.x >> 2;
  const int sel = (blockIdx.x >> 1) & 1;
  const int h = blockIdx.x & 1;
  const int* arr = sel ? dst : src;
  for (int i = threadIdx.x; i < 25000; i += 256) hist[i] = 0;
  __syncthreads();
  const int lo = h * 25000;
  const int slice = e >> 6;  // 12500
  const int base = b * slice;
  for (int i = base + threadIdx.x; i < base + slice; i += 256) {
    int v = arr[i] - lo;
    if ((unsigned)v < 25000u) atomicAdd(&hist[v], 1);  // LDS atomic: CU-local
  }
  __syncthreads();
  int* out = part + ((size_t)(sel * 2 + h) * HNB + b) * 25000;
  for (int i = threadIdx.x; i < 25000; i += 256) out[i] = hist[i];
}

// ---------------- fused: degree reduce + rs factors + block-level exclusive scan ----------------
__global__ __launch_bounds__(256) void degscan_kernel(const int* __restrict__ part, int* __restrict__ excl,
                                                      int* __restrict__ bsum, float* __restrict__ rs_out,
                                                      float* __restrict__ rs_in, int n) {
  int v = blockIdx.x * 256 + threadIdx.x;
  int is = 0;
  if (v < n) {
    const int h = (v >= 25000) ? 1 : 0;
    const int bin = v - h * 25000;
    const int* p0 = part + ((size_t)(0 + h) * HNB) * 25000 + bin;  // src -> out-deg
    const int* p1 = part + ((size_t)(2 + h) * HNB) * 25000 + bin;  // dst -> in-deg
    int os = 0;
#pragma unroll 8
    for (int b = 0; b < HNB; b++) {
      os += p0[(size_t)b * 25000];
      is += p1[(size_t)b * 25000];
    }
    rs_out[v] = rsqrtf((float)(os > 1 ? os : 1));
    rs_in[v] = rsqrtf((float)(is > 1 ? is : 1));
  }
  __shared__ int sh[256];
  sh[threadIdx.x] = is;
  __syncthreads();
  for (int off = 1; off < 256; off <<= 1) {
    int x = (threadIdx.x >= off) ? sh[threadIdx.x - off] : 0;
    __syncthreads();
    sh[threadIdx.x] += x;
    __syncthreads();
  }
  if (v < n) excl[v] = sh[threadIdx.x] - is;
  if (threadIdx.x == 255) bsum[blockIdx.x] = sh[255];
}

// ---------------- scan finalize: inline serial prefix of bsum (<=196 iters) ----------------
__global__ __launch_bounds__(256) void scan3_kernel(const int* __restrict__ excl, const int* __restrict__ bsum,
                                                    int* __restrict__ row_ptr, int n, int e) {
  int base = 0;
  for (int b = 0; b < blockIdx.x; b++) base += bsum[b];  // scalar-cached, uniform
  int i = blockIdx.x * 256 + threadIdx.x;
  if (i < n) row_ptr[i] = excl[i] + base;
  if (i == 0) row_ptr[n] = e;
}

// ---------------- per-(slice,half) start offsets ----------------
__global__ __launch_bounds__(256) void scanoffs_kernel(const int* __restrict__ part, const int* __restrict__ row_ptr,
                                                       int* __restrict__ offs, int n) {
  int v = blockIdx.x * 256 + threadIdx.x;
  if (v >= n) return;
  const int h = (v >= 25000) ? 1 : 0;
  const int bin = v - h * 25000;
  const int* p = part + ((size_t)(2 + h) * HNB) * 25000 + bin;  // dst partials
  int run = row_ptr[v];
#pragma unroll 8
  for (int b = 0; b < HNB; b++) {
    offs[((size_t)(b * 2 + h)) * 25000 + bin] = run;
    run += p[(size_t)b * 25000];
  }
}

// ---------------- CSR fill with LDS cursors (no global atomics) ----------------
__global__ __launch_bounds__(256) void fill2_kernel(const int* __restrict__ src, const int* __restrict__ dst,
                                                    const int* __restrict__ offs, int* __restrict__ csr_src, int e) {
  __shared__ int cur[25000];  // 100 KB
  const int b = blockIdx.x >> 1;
  const int h = blockIdx.x & 1;
  const int* o = offs + ((size_t)(b * 2 + h)) * 25000;
  for (int i = threadIdx.x; i < 25000; i += 256) cur[i] = o[i];
  __syncthreads();
  const int lo = h * 25000;
  const int slice = e >> 6;  // 12500
  const int base = b * slice;
  for (int i = base + threadIdx.x; i < base + slice; i += 256) {
    int v = dst[i] - lo;
    if ((unsigned)v < 25000u) {
      int pos = atomicAdd(&cur[v], 1);  // LDS atomic: CU-local
      csr_src[pos] = src[i];
    }
  }
}

// ---------------- weight pack: f32 [128][128] -> hi/lo bf16 in MFMA B-fragment order ----------------
__global__ __launch_bounds__(256) void convw_kernel(const float* __restrict__ W1, const float* __restrict__ W2,
                                                    const float* __restrict__ Wn1, const float* __restrict__ Wn2,
                                                    const float* __restrict__ Wg1, unsigned short* __restrict__ Wp) {
  const float* Ws[5] = {W1, W2, Wn1, Wn2, Wg1};
  const float* W = Ws[blockIdx.x];
  unsigned short* hi = Wp + (size_t)blockIdx.x * 32768;
  unsigned short* lo = hi + 16384;
  for (int s = threadIdx.x; s < 2048; s += 256) {
    int f = s >> 6, lane = s & 63;
    int ct = f >> 2, ks = f & 3;
    int col = ct * 16 + (lane & 15);
    int k0 = ks * 32 + ((lane >> 4) << 3);
    for (int j = 0; j < 8; j++) {
      float v = W[(k0 + j) * HD + col];
      unsigned short h = f2bf(v);
      hi[s * 8 + j] = h;
      lo[s * 8 + j] = f2bf(v - bf2f(h));
    }
  }
}

// ---------------- A-fragment load + transform + split-bf16 ----------------
template <int MODE>
__device__ inline void load_frag(const void* __restrict__ Ain, const float* __restrict__ bnp,
                                 int rA, int c0, bf16x8& ah, bf16x8& al) {
  float av[8];
  if (MODE == 0) {
    const float* ap = (const float*)Ain + (size_t)rA * HD + c0;
    float4 a0 = *reinterpret_cast<const float4*>(ap);
    float4 a1 = *reinterpret_cast<const float4*>(ap + 4);
    av[0] = a0.x; av[1] = a0.y; av[2] = a0.z; av[3] = a0.w;
    av[4] = a1.x; av[5] = a1.y; av[6] = a1.z; av[7] = a1.w;
  } else {
    const _Float16* ap = (const _Float16*)Ain + (size_t)rA * HD + c0;
    f16x8 a = *reinterpret_cast<const f16x8*>(ap);
#pragma unroll
    for (int j = 0; j < 8; j++) av[j] = (float)a[j];
  }
  if (MODE == 1) {
#pragma unroll
    for (int j = 0; j < 8; j++) {
      float x = fmaf(av[j], bnp[c0 + j], bnp[128 + c0 + j]);
      av[j] = x >= 0.f ? x : 0.01f * x;
    }
  }
#pragma unroll
  for (int j = 0; j < 8; j++) {
    unsigned short hh = f2bf(av[j]);
    ((short*)&ah)[j] = (short)hh;
    ((short*)&al)[j] = (short)f2bf(av[j] - bf2f(hh));
  }
}

// ---------------- MFMA GEMM: 32 rows/wave (W fragments reused across 2 A-tiles); fp16 out ----------------
// MODE 0: A f32.  MODE 1: A fp16 + BN + lrelu.  MODE 2: A fp16 plain.
template <int MODE>
__global__ __launch_bounds__(256) void mmfma_kernel(const void* __restrict__ Ain,
                                                    const float* __restrict__ bnp,
                                                    const unsigned short* __restrict__ Wp,
                                                    const float* __restrict__ rs,
                                                    const float* __restrict__ evec,
                                                    const float* __restrict__ erow,
                                                    _Float16* __restrict__ C, int n) {
  const int lane = threadIdx.x & 63;
  const int wv = threadIdx.x >> 6;
  const int rbase = (blockIdx.x * 4 + wv) * 32;
  if (rbase >= n) return;
  const int rA0 = min(rbase + (lane & 15), n - 1);
  const int rA1 = min(rbase + 16 + (lane & 15), n - 1);
  const int koff = (lane >> 4) << 3;
  const unsigned short* wlo = Wp + 16384;
  f32x4 acc0[8], acc1[8];
#pragma unroll
  for (int t = 0; t < 8; t++) {
    acc0[t] = (f32x4){0.f, 0.f, 0.f, 0.f};
    acc1[t] = (f32x4){0.f, 0.f, 0.f, 0.f};
  }
#pragma unroll
  for (int ks = 0; ks < 4; ks++) {
    const int c0 = ks * 32 + koff;
    bf16x8 ah0, al0, ah1, al1;
    load_frag<MODE>(Ain, bnp, rA0, c0, ah0, al0);
    load_frag<MODE>(Ain, bnp, rA1, c0, ah1, al1);
#pragma unroll
    for (int ct = 0; ct < 8; ct++) {
      int fo = ((ct * 4 + ks) * 64 + lane) * 8;
      bf16x8 bh = *reinterpret_cast<const bf16x8*>(Wp + fo);
      bf16x8 bl = *reinterpret_cast<const bf16x8*>(wlo + fo);
      acc0[ct] = __builtin_amdgcn_mfma_f32_16x16x32_bf16(ah0, bh, acc0[ct], 0, 0, 0);
      acc0[ct] = __builtin_amdgcn_mfma_f32_16x16x32_bf16(al0, bh, acc0[ct], 0, 0, 0);
      acc0[ct] = __builtin_amdgcn_mfma_f32_16x16x32_bf16(ah0, bl, acc0[ct], 0, 0, 0);
      acc1[ct] = __builtin_amdgcn_mfma_f32_16x16x32_bf16(ah1, bh, acc1[ct], 0, 0, 0);
      acc1[ct] = __builtin_amdgcn_mfma_f32_16x16x32_bf16(al1, bh, acc1[ct], 0, 0, 0);
      acc1[ct] = __builtin_amdgcn_mfma_f32_16x16x32_bf16(ah1, bl, acc1[ct], 0, 0, 0);
    }
  }
  const int cbase = lane & 15;
#define EPI(ACC, TOFF)                                                          \
  {                                                                             \
    const int r0 = rbase + (TOFF) + ((lane >> 4) << 2);                         \
    _Pragma("unroll") for (int i = 0; i < 4; i++) {                             \
      int r = r0 + i;                                                           \
      if (r < n) {                                                              \
        float rsv = rs[r];                                                      \
        float ev = (evec != nullptr) ? evec[r] : 0.f;                           \
        _Float16* crow = C + (size_t)r * HD + cbase;                            \
        _Pragma("unroll") for (int ct = 0; ct < 8; ct++) {                      \
          float v = ACC[ct][i];                                                 \
          if (evec != nullptr) v = fmaf(ev, erow[ct * 16 + cbase], v);          \
          crow[ct * 16] = (_Float16)(v * rsv);                                  \
        }                                                                       \
      }                                                                         \
    }                                                                           \
  }
  EPI(acc0, 0)
  EPI(acc1, 16)
#undef EPI
}

// ---------------- pull-mode aggregation; TAIL=1 fuses the [128]->[8] nodeout projection ----------------
template <int TAIL>
__global__ __launch_bounds__(256) void agg_kernel(const _Float16* __restrict__ Ys, const int* __restrict__ row_ptr,
                                                  const int* __restrict__ csr_src, const float* __restrict__ rs_in,
                                                  const float* __restrict__ bias, _Float16* __restrict__ out,
                                                  const float* __restrict__ Wnc, const float* __restrict__ bnc,
                                                  float* __restrict__ nout, int n, int do_lrelu) {
  const int wave = threadIdx.x >> 6;
  const int lane = threadIdx.x & 63;
  const int half = lane >> 5;
  const int li = lane & 31;
  const int node = blockIdx.x * 4 + wave;
  if (node >= n) return;
  const int beg = row_ptr[node], end = row_ptr[node + 1];
  const int cnt = end - beg;
  const int npairs = cnt >> 1;
  float a0 = 0.f, a1 = 0.f, a2 = 0.f, a3 = 0.f;
  int p = 0;
  for (; p + 8 <= npairs; p += 8) {
    int s[8];
#pragma unroll
    for (int j = 0; j < 8; j++) s[j] = csr_src[beg + 2 * (p + j) + half];
    f16x4 v[8];
#pragma unroll
    for (int j = 0; j < 8; j++) v[j] = reinterpret_cast<const f16x4*>(Ys + (size_t)s[j] * HD)[li];
#pragma unroll
    for (int j = 0; j < 8; j++) {
      a0 += (float)v[j].x;
      a1 += (float)v[j].y;
      a2 += (float)v[j].z;
      a3 += (float)v[j].w;
    }
  }
  for (; p < npairs; ++p) {
    int s = csr_src[beg + 2 * p + half];
    f16x4 v = reinterpret_cast<const f16x4*>(Ys + (size_t)s * HD)[li];
    a0 += (float)v.x;
    a1 += (float)v.y;
    a2 += (float)v.z;
    a3 += (float)v.w;
  }
  if ((cnt & 1) && half == 0) {  // odd tail -> half 0 only
    int s = csr_src[end - 1];
    f16x4 v = reinterpret_cast<const f16x4*>(Ys + (size_t)s * HD)[li];
    a0 += (float)v.x;
    a1 += (float)v.y;
    a2 += (float)v.z;
    a3 += (float)v.w;
  }
  a0 += __shfl_xor(a0, 32, 64);
  a1 += __shfl_xor(a1, 32, 64);
  a2 += __shfl_xor(a2, 32, 64);
  a3 += __shfl_xor(a3, 32, 64);
  if (half == 0) {
    float ri = rs_in[node];
    float4 b = reinterpret_cast<const float4*>(bias)[li];
    float o0 = fmaf(a0, ri, b.x);
    float o1 = fmaf(a1, ri, b.y);
    float o2 = fmaf(a2, ri, b.z);
    float o3 = fmaf(a3, ri, b.w);
    if (do_lrelu) {
      o0 = o0 >= 0.f ? o0 : 0.01f * o0;
      o1 = o1 >= 0.f ? o1 : 0.01f * o1;
      o2 = o2 >= 0.f ? o2 : 0.01f * o2;
      o3 = o3 >= 0.f ? o3 : 0.01f * o3;
    }
    if (TAIL == 0) {
      f16x4 ov = {(_Float16)o0, (_Float16)o1, (_Float16)o2, (_Float16)o3};
      reinterpret_cast<f16x4*>(out + (size_t)node * HD)[li] = ov;
    } else {
      // fused node_out: row (o0..o3 at cols 4li..4li+3) @ Wnc[128][8] + bnc
      float pr[8];
#pragma unroll
      for (int c = 0; c < 8; c++) pr[c] = 0.f;
      float ov[4] = {o0, o1, o2, o3};
#pragma unroll
      for (int j = 0; j < 4; j++) {
        const float* wr = Wnc + (size_t)(4 * li + j) * 8;
        float4 w0 = *reinterpret_cast<const float4*>(wr);
        float4 w1 = *reinterpret_cast<const float4*>(wr + 4);
        pr[0] = fmaf(ov[j], w0.x, pr[0]);
        pr[1] = fmaf(ov[j], w0.y, pr[1]);
        pr[2] = fmaf(ov[j], w0.z, pr[2]);
        pr[3] = fmaf(ov[j], w0.w, pr[3]);
        pr[4] = fmaf(ov[j], w1.x, pr[4]);
        pr[5] = fmaf(ov[j], w1.y, pr[5]);
        pr[6] = fmaf(ov[j], w1.z, pr[6]);
        pr[7] = fmaf(ov[j], w1.w, pr[7]);
      }
#pragma unroll
      for (int m = 16; m >= 1; m >>= 1) {
#pragma unroll
        for (int c = 0; c < 8; c++) pr[c] += __shfl_xor(pr[c], m, 64);
      }
      if (li == 0) {
        float4 r0 = make_float4(pr[0] + bnc[0], pr[1] + bnc[1], pr[2] + bnc[2], pr[3] + bnc[3]);
        float4 r1 = make_float4(pr[4] + bnc[4], pr[5] + bnc[5], pr[6] + bnc[6], pr[7] + bnc[7]);
        reinterpret_cast<float4*>(nout + (size_t)node * 8)[0] = r0;
        reinterpret_cast<float4*>(nout + (size_t)node * 8)[1] = r1;
      }
    }
  }
}

// ---------------- BN statistics: per-block partials (no atomics, no memset) ----------------
__global__ __launch_bounds__(256) void stats_kernel(const _Float16* __restrict__ Z, int n,
                                                    float* __restrict__ pstats) {
  int c = threadIdx.x & 127;
  int half = threadIdx.x >> 7;
  float s = 0.f, s2 = 0.f;
  for (int r = blockIdx.x * 2 + half; r < n; r += SB * 2) {
    float v = (float)Z[(size_t)r * HD + c];
    s += v;
    s2 = fmaf(v, v, s2);
  }
  __shared__ float ls[512];
  ls[threadIdx.x] = s;
  ls[256 + threadIdx.x] = s2;
  __syncthreads();
  if (threadIdx.x < 128) {
    pstats[(size_t)blockIdx.x * 256 + threadIdx.x] = ls[threadIdx.x] + ls[threadIdx.x + 128];
    pstats[(size_t)blockIdx.x * 256 + 128 + threadIdx.x] = ls[256 + threadIdx.x] + ls[384 + threadIdx.x];
  }
}

__global__ void bnfin_kernel(const float* __restrict__ pstats, const float* __restrict__ gamma,
                             const float* __restrict__ beta, float* __restrict__ bnp, float n) {
  int c = threadIdx.x;  // 128
  float s = 0.f, s2 = 0.f;
  for (int j = 0; j < SB; j++) {
    s += pstats[(size_t)j * 256 + c];
    s2 += pstats[(size_t)j * 256 + 128 + c];
  }
  float mu = s / n;
  float var = s2 / n - mu * mu;
  if (var < 0.f) var = 0.f;
  float sc = gamma[c] * rsqrtf(var + 1e-5f);
  bnp[c] = sc;
  bnp[128 + c] = fmaf(-mu, sc, beta[c]);
}

// ---------------- graph mean stage 1: 64 graphs x GK chunk-blocks, fp16 input ----------------
__global__ __launch_bounds__(256) void gpart_kernel(const _Float16* __restrict__ HG, const int* __restrict__ gid,
                                                    float* __restrict__ partial, int n) {
  const int g = blockIdx.x >> 4;  // GK==16
  const int j = blockIdx.x & 15;
  int lo = 0, hi = n;
  while (lo < hi) { int mid = (lo + hi) >> 1; if (gid[mid] < g) lo = mid + 1; else hi = mid; }
  const int beg = lo;
  lo = 0; hi = n;
  while (lo < hi) { int mid = (lo + hi) >> 1; if (gid[mid] < g + 1) lo = mid + 1; else hi = mid; }
  const int end = lo;
  const int len = end - beg;
  const int chunk = (len + GK - 1) / GK;
  const int r0 = beg + j * chunk;
  const int r1 = min(r0 + chunk, end);

  const int c = threadIdx.x & 127;
  const int half = threadIdx.x >> 7;
  float s = 0.f;
  for (int r = r0 + half; r < r1; r += 2)
    s += (float)HG[(size_t)r * HD + c];

  __shared__ float sh[256];
  sh[threadIdx.x] = s;
  __syncthreads();
  if (threadIdx.x < 128)
    partial[(size_t)blockIdx.x * HD + threadIdx.x] = sh[threadIdx.x] + sh[threadIdx.x + 128];
}

// ---------------- graph mean stage 2: reduce GK partials, scale, @Wgc + bgc ----------------
__global__ __launch_bounds__(128) void gfin_kernel(const float* __restrict__ partial, const int* __restrict__ gid,
                                                   const float* __restrict__ Wgc, const float* __restrict__ bgc,
                                                   float* __restrict__ out, int n) {
  const int g = blockIdx.x;
  int lo = 0, hi = n;
  while (lo < hi) { int mid = (lo + hi) >> 1; if (gid[mid] < g) lo = mid + 1; else hi = mid; }
  const int beg = lo;
  lo = 0; hi = n;
  while (lo < hi) { int mid = (lo + hi) >> 1; if (gid[mid] < g + 1) lo = mid + 1; else hi = mid; }
  const int end = lo;
  float cntf = (float)(end - beg);
  float inv = 1.f / (cntf > 1.f ? cntf : 1.f);

  const int c = threadIdx.x;  // 128
  float s = 0.f;
#pragma unroll
  for (int j = 0; j < GK; j++) s += partial[(size_t)(g * GK + j) * HD + c];
  __shared__ float sh[128];
  sh[c] = s * inv;
  __syncthreads();
  if (c < 4) {
    float acc = bgc[c];
    for (int k = 0; k < HD; k++) acc = fmaf(sh[k], Wgc[k * 4 + c], acc);
    out[g * 4 + c] = acc;
  }
}

extern "C" void kernel_launch(void* const* d_in, const int* in_sizes, int n_in,
                              void* d_out, int out_size, void* d_ws, size_t ws_size,
                              hipStream_t stream) {
  const float* node_feat = (const float*)d_in[0];
  const float* nodetype = (const float*)d_in[1];
  // d_in[2] edge_feat: dead branch, unused
  const float* W1 = (const float*)d_in[3];
  const float* b1 = (const float*)d_in[4];
  const float* g1 = (const float*)d_in[5];
  const float* be1 = (const float*)d_in[6];
  const float* W2 = (const float*)d_in[7];
  const float* b2 = (const float*)d_in[8];
  const float* g2 = (const float*)d_in[9];
  const float* be2 = (const float*)d_in[10];
  // 11 We, 12 b_e: dead
  const float* Wn1 = (const float*)d_in[13];
  const float* bn1 = (const float*)d_in[14];
  const float* Wn2 = (const float*)d_in[15];
  const float* bn2 = (const float*)d_in[16];
  const float* Wnc = (const float*)d_in[17];
  const float* bnc = (const float*)d_in[18];
  const float* Wg1 = (const float*)d_in[19];
  const float* bg1 = (const float*)d_in[20];
  const float* Wgc = (const float*)d_in[21];
  const float* bgc = (const float*)d_in[22];
  const int* src = (const int*)d_in[23];
  const int* dst = (const int*)d_in[24];
  const int* gid = (const int*)d_in[25];

  const int n = NN, e = NE;

  // ---- workspace carve (256B aligned) ----
  char* w = (char*)d_ws;
  auto alloc = [&](size_t bytes) -> void* {
    void* p = (void*)w;
    w += (bytes + 255) & ~(size_t)255;
    return p;
  };
  _Float16* T1 = (_Float16*)alloc((size_t)n * HD * 4);  // fp16 mm out (half used); aliases deghist partials (25.6 MB)
  _Float16* AX = (_Float16*)alloc((size_t)n * HD * 2);  // fp16 agg out L1/L3/L5 (disjoint live ranges)
  _Float16* A2 = (_Float16*)alloc((size_t)n * HD * 2);  // fp16 agg out L2; prologue aliases fill offsets (12.8 MB)
  int* hpart = (int*)T1;                                // 4*HNB*25000*4 B = 25.6 MB
  int* offs = (int*)A2;                                 // 2*HNB*25000*4 B = 12.8 MB; dead before L2 agg
  int* csr_src = (int*)alloc((size_t)e * 4);
  int* row_ptr = (int*)alloc((size_t)(n + 1) * 4);
  int* excl = (int*)alloc((size_t)n * 4);
  int* bsum = (int*)alloc(256 * 4);
  float* rs_out = (float*)alloc((size_t)n * 4);
  float* rs_in = (float*)alloc((size_t)n * 4);
  float* pstats = (float*)alloc((size_t)SB * 256 * 4);
  float* bnp1 = (float*)alloc(256 * 4);
  float* bnp2 = (float*)alloc(256 * 4);
  unsigned short* Wp = (unsigned short*)alloc(5 * 32768 * 2);
  float* partial = (float*)alloc((size_t)64 * GK * HD * 4);

  const int NB = (n + 255) / 256;
  const int MMB = (n + 127) / 128;  // 391: 4 waves x 32 rows
  const int AGB = (n + 3) / 4;

  // ---- weight pack ----
  convw_kernel<<<5, 256, 0, stream>>>(W1, W2, Wn1, Wn2, Wg1, Wp);

  // ---- degrees + CSR build (fully atomic-free on global memory) ----
  deghist_kernel<<<HNB * 4, 256, 0, stream>>>(src, dst, hpart, e);
  degscan_kernel<<<NB, 256, 0, stream>>>(hpart, excl, bsum, rs_out, rs_in, n);
  scan3_kernel<<<NB, 256, 0, stream>>>(excl, bsum, row_ptr, n, e);
  scanoffs_kernel<<<NB, 256, 0, stream>>>(hpart, row_ptr, offs, n);
  fill2_kernel<<<HNB * 2, 256, 0, stream>>>(src, dst, offs, csr_src, e);

  // ---- layer 1 (f32 node_feat in) ----
  mmfma_kernel<0><<<MMB, 256, 0, stream>>>(node_feat, nullptr, Wp + 0 * 32768, rs_out, nullptr, nullptr, T1, n);
  agg_kernel<0><<<AGB, 256, 0, stream>>>(T1, row_ptr, csr_src, rs_in, b1, AX, nullptr, nullptr, nullptr, n, 0);
  stats_kernel<<<SB, 256, 0, stream>>>(AX, n, pstats);
  bnfin_kernel<<<1, 128, 0, stream>>>(pstats, g1, be1, bnp1, (float)n);

  // ---- layer 2 (fp16 in, BN1+lrelu fused) ----
  mmfma_kernel<1><<<MMB, 256, 0, stream>>>(AX, bnp1, Wp + 1 * 32768, rs_out, nullptr, nullptr, T1, n);
  agg_kernel<0><<<AGB, 256, 0, stream>>>(T1, row_ptr, csr_src, rs_in, b2, A2, nullptr, nullptr, nullptr, n, 0);
  stats_kernel<<<SB, 256, 0, stream>>>(A2, n, pstats);
  bnfin_kernel<<<1, 128, 0, stream>>>(pstats, g2, be2, bnp2, (float)n);

  // ---- layer 3 (fp16 in, BN2 fused) ----
  mmfma_kernel<1><<<MMB, 256, 0, stream>>>(A2, bnp2, Wp + 2 * 32768, rs_out, nullptr, nullptr, T1, n);
  agg_kernel<0><<<AGB, 256, 0, stream>>>(T1, row_ptr, csr_src, rs_in, bn1, AX, nullptr, nullptr, nullptr, n, 1);

  // ---- layer 4 (fp16 in, plain) + fused node_out projection ----
  mmfma_kernel<2><<<MMB, 256, 0, stream>>>(AX, nullptr, Wp + 3 * 32768, rs_out, nullptr, nullptr, T1, n);
  agg_kernel<1><<<AGB, 256, 0, stream>>>(T1, row_ptr, csr_src, rs_in, bn2, nullptr, Wnc, bnc, (float*)d_out, n, 1);

  // ---- layer 5 (fp16 in, BN2 fused; rank-1 fold of nodetype) ----
  mmfma_kernel<1><<<MMB, 256, 0, stream>>>(A2, bnp2, Wp + 4 * 32768, rs_out, nodetype, Wg1 + HD * HD, T1, n);
  agg_kernel<0><<<AGB, 256, 0, stream>>>(T1, row_ptr, csr_src, rs_in, bg1, AX, nullptr, nullptr, nullptr, n, 1);

  // ---- graph mean (two-stage, no atomics) + graph_out ----
  gpart_kernel<<<64 * GK, 256, 0, stream>>>(AX, gid, partial, n);
  gfin_kernel<<<64, 128, 0, stream>>>(partial, gid, Wgc, bgc, (float*)d_out + (size_t)n * 8, n);
}

// Round 11
// 505.169 us; speedup vs baseline: 1.0433x; 1.0433x over previous
//
#include <hip/hip_runtime.h>
#include <cstdint>
#include <cstddef>

#define NN 50000
#define NE 800000
#define HD 128
#define GK 16     // chunk-blocks per graph in gpart
#define HNB 64    // edge-slice blocks per (array,half) in deghist
#define SB 128    // stats partial blocks

typedef __attribute__((ext_vector_type(8))) short bf16x8;
typedef __attribute__((ext_vector_type(4))) float f32x4;
typedef _Float16 f16x4 __attribute__((ext_vector_type(4)));
typedef _Float16 f16x8 __attribute__((ext_vector_type(8)));

__device__ inline unsigned short f2bf(float x) {
  unsigned u = __float_as_uint(x);
  u += 0x7FFF + ((u >> 16) & 1);  // round-to-nearest-even
  return (unsigned short)(u >> 16);
}
__device__ inline float bf2f(unsigned short h) { return __uint_as_float((unsigned)h << 16); }

// ---------------- degree histogram via LDS privatization (no global atomics) ----------------
__global__ __launch_bounds__(256) void deghist_kernel(const int* __restrict__ src, const int* __restrict__ dst,
                                                      int* __restrict__ part, int e) {
  __shared__ int hist[25000];  // 100 KB
  const int b = blockIdx.x >> 2;
  const int sel = (blockIdx.x >> 1) & 1;
  const int h = blockIdx.x & 1;
  const int* arr = sel ? dst : src;
  for (int i = threadIdx.x; i < 25000; i += 256) hist[i] = 0;
  __syncthreads();
  const int lo = h * 25000;
  const int slice = e >> 6;  // 12500
  const int base = b * slice;
  for (int i = base + threadIdx.x; i < base + slice; i += 256) {
    int v = arr[i] - lo;
    if ((unsigned)v < 25000u) atomicAdd(&hist[v], 1);  // LDS atomic: CU-local
  }
  __syncthreads();
  int* out = part + ((size_t)(sel * 2 + h) * HNB + b) * 25000;
  for (int i = threadIdx.x; i < 25000; i += 256) out[i] = hist[i];
}

// ---------------- fused: degree reduce + rs factors + block-level exclusive scan ----------------
__global__ __launch_bounds__(256) void degscan_kernel(const int* __restrict__ part, int* __restrict__ excl,
                                                      int* __restrict__ bsum, float* __restrict__ rs_out,
                                                      float* __restrict__ rs_in, int n) {
  int v = blockIdx.x * 256 + threadIdx.x;
  int is = 0;
  if (v < n) {
    const int h = (v >= 25000) ? 1 : 0;
    const int bin = v - h * 25000;
    const int* p0 = part + ((size_t)(0 + h) * HNB) * 25000 + bin;  // src -> out-deg
    const int* p1 = part + ((size_t)(2 + h) * HNB) * 25000 + bin;  // dst -> in-deg
    int os = 0;
#pragma unroll 8
    for (int b = 0; b < HNB; b++) {
      os += p0[(size_t)b * 25000];
      is += p1[(size_t)b * 25000];
    }
    rs_out[v] = rsqrtf((float)(os > 1 ? os : 1));
    rs_in[v] = rsqrtf((float)(is > 1 ? is : 1));
  }
  __shared__ int sh[256];
  sh[threadIdx.x] = is;
  __syncthreads();
  for (int off = 1; off < 256; off <<= 1) {
    int x = (threadIdx.x >= off) ? sh[threadIdx.x - off] : 0;
    __syncthreads();
    sh[threadIdx.x] += x;
    __syncthreads();
  }
  if (v < n) excl[v] = sh[threadIdx.x] - is;
  if (threadIdx.x == 255) bsum[blockIdx.x] = sh[255];
}

// ---------------- scan finalize: inline serial prefix of bsum (<=196 iters) ----------------
__global__ __launch_bounds__(256) void scan3_kernel(const int* __restrict__ excl, const int* __restrict__ bsum,
                                                    int* __restrict__ row_ptr, int n, int e) {
  int base = 0;
  for (int b = 0; b < blockIdx.x; b++) base += bsum[b];  // scalar-cached, uniform
  int i = blockIdx.x * 256 + threadIdx.x;
  if (i < n) row_ptr[i] = excl[i] + base;
  if (i == 0) row_ptr[n] = e;
}

// ---------------- per-(slice,half) start offsets ----------------
__global__ __launch_bounds__(256) void scanoffs_kernel(const int* __restrict__ part, const int* __restrict__ row_ptr,
                                                       int* __restrict__ offs, int n) {
  int v = blockIdx.x * 256 + threadIdx.x;
  if (v >= n) return;
  const int h = (v >= 25000) ? 1 : 0;
  const int bin = v - h * 25000;
  const int* p = part + ((size_t)(2 + h) * HNB) * 25000 + bin;  // dst partials
  int run = row_ptr[v];
#pragma unroll 8
  for (int b = 0; b < HNB; b++) {
    offs[((size_t)(b * 2 + h)) * 25000 + bin] = run;
    run += p[(size_t)b * 25000];
  }
}

// ---------------- CSR fill with LDS cursors (no global atomics) ----------------
__global__ __launch_bounds__(256) void fill2_kernel(const int* __restrict__ src, const int* __restrict__ dst,
                                                    const int* __restrict__ offs, int* __restrict__ csr_src, int e) {
  __shared__ int cur[25000];  // 100 KB
  const int b = blockIdx.x >> 1;
  const int h = blockIdx.x & 1;
  const int* o = offs + ((size_t)(b * 2 + h)) * 25000;
  for (int i = threadIdx.x; i < 25000; i += 256) cur[i] = o[i];
  __syncthreads();
  const int lo = h * 25000;
  const int slice = e >> 6;  // 12500
  const int base = b * slice;
  for (int i = base + threadIdx.x; i < base + slice; i += 256) {
    int v = dst[i] - lo;
    if ((unsigned)v < 25000u) {
      int pos = atomicAdd(&cur[v], 1);  // LDS atomic: CU-local
      csr_src[pos] = src[i];
    }
  }
}

// ---------------- weight pack: f32 [128][128] -> hi/lo bf16 in MFMA B-fragment order ----------------
__global__ __launch_bounds__(256) void convw_kernel(const float* __restrict__ W1, const float* __restrict__ W2,
                                                    const float* __restrict__ Wn1, const float* __restrict__ Wn2,
                                                    const float* __restrict__ Wg1, unsigned short* __restrict__ Wp) {
  const float* Ws[5] = {W1, W2, Wn1, Wn2, Wg1};
  const float* W = Ws[blockIdx.x];
  unsigned short* hi = Wp + (size_t)blockIdx.x * 32768;
  unsigned short* lo = hi + 16384;
  for (int s = threadIdx.x; s < 2048; s += 256) {
    int f = s >> 6, lane = s & 63;
    int ct = f >> 2, ks = f & 3;
    int col = ct * 16 + (lane & 15);
    int k0 = ks * 32 + ((lane >> 4) << 3);
    for (int j = 0; j < 8; j++) {
      float v = W[(k0 + j) * HD + col];
      unsigned short h = f2bf(v);
      hi[s * 8 + j] = h;
      lo[s * 8 + j] = f2bf(v - bf2f(h));
    }
  }
}

// ---------------- MFMA GEMM with fused input transform; fp16 output (16 rows/wave, R9 config) ----------------
// MODE 0: A is f32, no BN (layer 1).  MODE 1: A is fp16, BN+lrelu fused.  MODE 2: A is fp16, plain.
// C[r][c] = fp16( (sum_k A'[r][k]*W[k][c] (+ evec[r]*erow[c])) * rs[r] )
template <int MODE>
__global__ __launch_bounds__(256) void mmfma_kernel(const void* __restrict__ Ain,
                                                    const float* __restrict__ bnp,
                                                    const unsigned short* __restrict__ Wp,
                                                    const float* __restrict__ rs,
                                                    const float* __restrict__ evec,
                                                    const float* __restrict__ erow,
                                                    _Float16* __restrict__ C, int n) {
  const int lane = threadIdx.x & 63;
  const int wv = threadIdx.x >> 6;
  const int rbase = (blockIdx.x * 4 + wv) * 16;
  if (rbase >= n) return;
  const int rA = min(rbase + (lane & 15), n - 1);
  const int koff = (lane >> 4) << 3;
  const unsigned short* wlo = Wp + 16384;
  f32x4 acc[8];
#pragma unroll
  for (int t = 0; t < 8; t++) acc[t] = (f32x4){0.f, 0.f, 0.f, 0.f};
#pragma unroll
  for (int ks = 0; ks < 4; ks++) {
    const int c0 = ks * 32 + koff;
    float av[8];
    if (MODE == 0) {
      const float* ap = (const float*)Ain + (size_t)rA * HD + c0;
      float4 a0 = *reinterpret_cast<const float4*>(ap);
      float4 a1 = *reinterpret_cast<const float4*>(ap + 4);
      av[0] = a0.x; av[1] = a0.y; av[2] = a0.z; av[3] = a0.w;
      av[4] = a1.x; av[5] = a1.y; av[6] = a1.z; av[7] = a1.w;
    } else {
      const _Float16* ap = (const _Float16*)Ain + (size_t)rA * HD + c0;
      f16x8 a = *reinterpret_cast<const f16x8*>(ap);
#pragma unroll
      for (int j = 0; j < 8; j++) av[j] = (float)a[j];
    }
    if (MODE == 1) {
#pragma unroll
      for (int j = 0; j < 8; j++) {
        float x = fmaf(av[j], bnp[c0 + j], bnp[128 + c0 + j]);
        av[j] = x >= 0.f ? x : 0.01f * x;
      }
    }
    bf16x8 ah, al;
#pragma unroll
    for (int j = 0; j < 8; j++) {
      unsigned short hh = f2bf(av[j]);
      ((short*)&ah)[j] = (short)hh;
      ((short*)&al)[j] = (short)f2bf(av[j] - bf2f(hh));
    }
#pragma unroll
    for (int ct = 0; ct < 8; ct++) {
      int fo = ((ct * 4 + ks) * 64 + lane) * 8;
      bf16x8 bh = *reinterpret_cast<const bf16x8*>(Wp + fo);
      bf16x8 bl = *reinterpret_cast<const bf16x8*>(wlo + fo);
      acc[ct] = __builtin_amdgcn_mfma_f32_16x16x32_bf16(ah, bh, acc[ct], 0, 0, 0);
      acc[ct] = __builtin_amdgcn_mfma_f32_16x16x32_bf16(al, bh, acc[ct], 0, 0, 0);
      acc[ct] = __builtin_amdgcn_mfma_f32_16x16x32_bf16(ah, bl, acc[ct], 0, 0, 0);
    }
  }
  const int r0 = rbase + ((lane >> 4) << 2);
  const int cbase = lane & 15;
#pragma unroll
  for (int i = 0; i < 4; i++) {
    int r = r0 + i;
    if (r < n) {
      float rsv = rs[r];
      float ev = (evec != nullptr) ? evec[r] : 0.f;
      _Float16* crow = C + (size_t)r * HD + cbase;
#pragma unroll
      for (int ct = 0; ct < 8; ct++) {
        float v = acc[ct][i];
        if (evec != nullptr) v = fmaf(ev, erow[ct * 16 + cbase], v);
        crow[ct * 16] = (_Float16)(v * rsv);
      }
    }
  }
}

// ---------------- pull-mode aggregation: wave = node, 2 edges/load, fp16 in AND out (R9 config) ----------------
__global__ __launch_bounds__(256) void agg_kernel(const _Float16* __restrict__ Ys, const int* __restrict__ row_ptr,
                                                  const int* __restrict__ csr_src, const float* __restrict__ rs_in,
                                                  const float* __restrict__ bias, _Float16* __restrict__ out,
                                                  int n, int do_lrelu) {
  const int wave = threadIdx.x >> 6;
  const int lane = threadIdx.x & 63;
  const int half = lane >> 5;
  const int li = lane & 31;
  const int node = blockIdx.x * 4 + wave;
  if (node >= n) return;
  const int beg = row_ptr[node], end = row_ptr[node + 1];
  const int cnt = end - beg;
  const int npairs = cnt >> 1;
  float a0 = 0.f, a1 = 0.f, a2 = 0.f, a3 = 0.f;
  int p = 0;
  for (; p + 8 <= npairs; p += 8) {
    int s[8];
#pragma unroll
    for (int j = 0; j < 8; j++) s[j] = csr_src[beg + 2 * (p + j) + half];
    f16x4 v[8];
#pragma unroll
    for (int j = 0; j < 8; j++) v[j] = reinterpret_cast<const f16x4*>(Ys + (size_t)s[j] * HD)[li];
#pragma unroll
    for (int j = 0; j < 8; j++) {
      a0 += (float)v[j].x;
      a1 += (float)v[j].y;
      a2 += (float)v[j].z;
      a3 += (float)v[j].w;
    }
  }
  for (; p < npairs; ++p) {
    int s = csr_src[beg + 2 * p + half];
    f16x4 v = reinterpret_cast<const f16x4*>(Ys + (size_t)s * HD)[li];
    a0 += (float)v.x;
    a1 += (float)v.y;
    a2 += (float)v.z;
    a3 += (float)v.w;
  }
  if ((cnt & 1) && half == 0) {  // odd tail -> half 0 only
    int s = csr_src[end - 1];
    f16x4 v = reinterpret_cast<const f16x4*>(Ys + (size_t)s * HD)[li];
    a0 += (float)v.x;
    a1 += (float)v.y;
    a2 += (float)v.z;
    a3 += (float)v.w;
  }
  a0 += __shfl_xor(a0, 32, 64);
  a1 += __shfl_xor(a1, 32, 64);
  a2 += __shfl_xor(a2, 32, 64);
  a3 += __shfl_xor(a3, 32, 64);
  if (half == 0) {
    float ri = rs_in[node];
    float4 b = reinterpret_cast<const float4*>(bias)[li];
    float o0 = fmaf(a0, ri, b.x);
    float o1 = fmaf(a1, ri, b.y);
    float o2 = fmaf(a2, ri, b.z);
    float o3 = fmaf(a3, ri, b.w);
    if (do_lrelu) {
      o0 = o0 >= 0.f ? o0 : 0.01f * o0;
      o1 = o1 >= 0.f ? o1 : 0.01f * o1;
      o2 = o2 >= 0.f ? o2 : 0.01f * o2;
      o3 = o3 >= 0.f ? o3 : 0.01f * o3;
    }
    f16x4 ov = {(_Float16)o0, (_Float16)o1, (_Float16)o2, (_Float16)o3};
    reinterpret_cast<f16x4*>(out + (size_t)node * HD)[li] = ov;
  }
}

// ---------------- BN statistics: per-block partials (no atomics, no memset) ----------------
__global__ __launch_bounds__(256) void stats_kernel(const _Float16* __restrict__ Z, int n,
                                                    float* __restrict__ pstats) {
  int c = threadIdx.x & 127;
  int half = threadIdx.x >> 7;
  float s = 0.f, s2 = 0.f;
  for (int r = blockIdx.x * 2 + half; r < n; r += SB * 2) {
    float v = (float)Z[(size_t)r * HD + c];
    s += v;
    s2 = fmaf(v, v, s2);
  }
  __shared__ float ls[512];
  ls[threadIdx.x] = s;
  ls[256 + threadIdx.x] = s2;
  __syncthreads();
  if (threadIdx.x < 128) {
    pstats[(size_t)blockIdx.x * 256 + threadIdx.x] = ls[threadIdx.x] + ls[threadIdx.x + 128];
    pstats[(size_t)blockIdx.x * 256 + 128 + threadIdx.x] = ls[256 + threadIdx.x] + ls[384 + threadIdx.x];
  }
}

__global__ void bnfin_kernel(const float* __restrict__ pstats, const float* __restrict__ gamma,
                             const float* __restrict__ beta, float* __restrict__ bnp, float n) {
  int c = threadIdx.x;  // 128
  float s = 0.f, s2 = 0.f;
  for (int j = 0; j < SB; j++) {
    s += pstats[(size_t)j * 256 + c];
    s2 += pstats[(size_t)j * 256 + 128 + c];
  }
  float mu = s / n;
  float var = s2 / n - mu * mu;
  if (var < 0.f) var = 0.f;
  float sc = gamma[c] * rsqrtf(var + 1e-5f);
  bnp[c] = sc;
  bnp[128 + c] = fmaf(-mu, sc, beta[c]);
}

// ---------------- node_out = X@Wnc + b_nc  ([n,128]@[128,8], fp16 X) ----------------
__global__ __launch_bounds__(256) void nodeout_kernel(const _Float16* __restrict__ X, const float* __restrict__ Wnc,
                                                      const float* __restrict__ b, float* __restrict__ out, int n) {
  __shared__ float Wl[HD * 8];
  __shared__ float bl[8];
  for (int i = threadIdx.x; i < HD * 8; i += 256) Wl[i] = Wnc[i];
  if (threadIdx.x < 8) bl[threadIdx.x] = b[threadIdx.x];
  __syncthreads();
  int t = blockIdx.x * 256 + threadIdx.x;
  int r = t >> 3, c = t & 7;
  if (r >= n) return;
  const _Float16* x = X + (size_t)r * HD;
  float acc = bl[c];
  for (int k = 0; k < HD; k += 4) {
    f16x4 a = *reinterpret_cast<const f16x4*>(x + k);
    acc = fmaf((float)a.x, Wl[k * 8 + c], acc);
    acc = fmaf((float)a.y, Wl[(k + 1) * 8 + c], acc);
    acc = fmaf((float)a.z, Wl[(k + 2) * 8 + c], acc);
    acc = fmaf((float)a.w, Wl[(k + 3) * 8 + c], acc);
  }
  out[(size_t)r * 8 + c] = acc;
}

// ---------------- graph mean stage 1: 64 graphs x GK chunk-blocks, fp16 input ----------------
__global__ __launch_bounds__(256) void gpart_kernel(const _Float16* __restrict__ HG, const int* __restrict__ gid,
                                                    float* __restrict__ partial, int n) {
  const int g = blockIdx.x >> 4;  // GK==16
  const int j = blockIdx.x & 15;
  int lo = 0, hi = n;
  while (lo < hi) { int mid = (lo + hi) >> 1; if (gid[mid] < g) lo = mid + 1; else hi = mid; }
  const int beg = lo;
  lo = 0; hi = n;
  while (lo < hi) { int mid = (lo + hi) >> 1; if (gid[mid] < g + 1) lo = mid + 1; else hi = mid; }
  const int end = lo;
  const int len = end - beg;
  const int chunk = (len + GK - 1) / GK;
  const int r0 = beg + j * chunk;
  const int r1 = min(r0 + chunk, end);

  const int c = threadIdx.x & 127;
  const int half = threadIdx.x >> 7;
  float s = 0.f;
  for (int r = r0 + half; r < r1; r += 2)
    s += (float)HG[(size_t)r * HD + c];

  __shared__ float sh[256];
  sh[threadIdx.x] = s;
  __syncthreads();
  if (threadIdx.x < 128)
    partial[(size_t)blockIdx.x * HD + threadIdx.x] = sh[threadIdx.x] + sh[threadIdx.x + 128];
}

// ---------------- graph mean stage 2: reduce GK partials, scale, @Wgc + bgc ----------------
__global__ __launch_bounds__(128) void gfin_kernel(const float* __restrict__ partial, const int* __restrict__ gid,
                                                   const float* __restrict__ Wgc, const float* __restrict__ bgc,
                                                   float* __restrict__ out, int n) {
  const int g = blockIdx.x;
  int lo = 0, hi = n;
  while (lo < hi) { int mid = (lo + hi) >> 1; if (gid[mid] < g) lo = mid + 1; else hi = mid; }
  const int beg = lo;
  lo = 0; hi = n;
  while (lo < hi) { int mid = (lo + hi) >> 1; if (gid[mid] < g + 1) lo = mid + 1; else hi = mid; }
  const int end = lo;
  float cntf = (float)(end - beg);
  float inv = 1.f / (cntf > 1.f ? cntf : 1.f);

  const int c = threadIdx.x;  // 128
  float s = 0.f;
#pragma unroll
  for (int j = 0; j < GK; j++) s += partial[(size_t)(g * GK + j) * HD + c];
  __shared__ float sh[128];
  sh[c] = s * inv;
  __syncthreads();
  if (c < 4) {
    float acc = bgc[c];
    for (int k = 0; k < HD; k++) acc = fmaf(sh[k], Wgc[k * 4 + c], acc);
    out[g * 4 + c] = acc;
  }
}

extern "C" void kernel_launch(void* const* d_in, const int* in_sizes, int n_in,
                              void* d_out, int out_size, void* d_ws, size_t ws_size,
                              hipStream_t stream) {
  const float* node_feat = (const float*)d_in[0];
  const float* nodetype = (const float*)d_in[1];
  // d_in[2] edge_feat: dead branch, unused
  const float* W1 = (const float*)d_in[3];
  const float* b1 = (const float*)d_in[4];
  const float* g1 = (const float*)d_in[5];
  const float* be1 = (const float*)d_in[6];
  const float* W2 = (const float*)d_in[7];
  const float* b2 = (const float*)d_in[8];
  const float* g2 = (const float*)d_in[9];
  const float* be2 = (const float*)d_in[10];
  // 11 We, 12 b_e: dead
  const float* Wn1 = (const float*)d_in[13];
  const float* bn1 = (const float*)d_in[14];
  const float* Wn2 = (const float*)d_in[15];
  const float* bn2 = (const float*)d_in[16];
  const float* Wnc = (const float*)d_in[17];
  const float* bnc = (const float*)d_in[18];
  const float* Wg1 = (const float*)d_in[19];
  const float* bg1 = (const float*)d_in[20];
  const float* Wgc = (const float*)d_in[21];
  const float* bgc = (const float*)d_in[22];
  const int* src = (const int*)d_in[23];
  const int* dst = (const int*)d_in[24];
  const int* gid = (const int*)d_in[25];

  const int n = NN, e = NE;

  // ---- workspace carve (256B aligned) ----
  char* w = (char*)d_ws;
  auto alloc = [&](size_t bytes) -> void* {
    void* p = (void*)w;
    w += (bytes + 255) & ~(size_t)255;
    return p;
  };
  _Float16* T1 = (_Float16*)alloc((size_t)n * HD * 4);  // fp16 mm out (half used); aliases deghist partials (25.6 MB)
  _Float16* AX = (_Float16*)alloc((size_t)n * HD * 2);  // fp16 agg out L1/L3/L4/L5 (disjoint live ranges)
  _Float16* A2 = (_Float16*)alloc((size_t)n * HD * 2);  // fp16 agg out L2; prologue aliases fill offsets (12.8 MB)
  int* hpart = (int*)T1;                                // 4*HNB*25000*4 B = 25.6 MB
  int* offs = (int*)A2;                                 // 2*HNB*25000*4 B = 12.8 MB; dead before L2 agg
  int* csr_src = (int*)alloc((size_t)e * 4);
  int* row_ptr = (int*)alloc((size_t)(n + 1) * 4);
  int* excl = (int*)alloc((size_t)n * 4);
  int* bsum = (int*)alloc(256 * 4);
  float* rs_out = (float*)alloc((size_t)n * 4);
  float* rs_in = (float*)alloc((size_t)n * 4);
  float* pstats = (float*)alloc((size_t)SB * 256 * 4);
  float* bnp1 = (float*)alloc(256 * 4);
  float* bnp2 = (float*)alloc(256 * 4);
  unsigned short* Wp = (unsigned short*)alloc(5 * 32768 * 2);
  float* partial = (float*)alloc((size_t)64 * GK * HD * 4);

  const int NB = (n + 255) / 256;
  const int MMB = (n + 63) / 64;  // 782: 4 waves x 16 rows (R9 config)
  const int AGB = (n + 3) / 4;
  const int NOB = (n * 8 + 255) / 256;

  // ---- weight pack ----
  convw_kernel<<<5, 256, 0, stream>>>(W1, W2, Wn1, Wn2, Wg1, Wp);

  // ---- degrees + CSR build (fully atomic-free on global memory) ----
  deghist_kernel<<<HNB * 4, 256, 0, stream>>>(src, dst, hpart, e);
  degscan_kernel<<<NB, 256, 0, stream>>>(hpart, excl, bsum, rs_out, rs_in, n);
  scan3_kernel<<<NB, 256, 0, stream>>>(excl, bsum, row_ptr, n, e);
  scanoffs_kernel<<<NB, 256, 0, stream>>>(hpart, row_ptr, offs, n);
  fill2_kernel<<<HNB * 2, 256, 0, stream>>>(src, dst, offs, csr_src, e);

  // ---- layer 1 (f32 node_feat in) ----
  mmfma_kernel<0><<<MMB, 256, 0, stream>>>(node_feat, nullptr, Wp + 0 * 32768, rs_out, nullptr, nullptr, T1, n);
  agg_kernel<<<AGB, 256, 0, stream>>>(T1, row_ptr, csr_src, rs_in, b1, AX, n, 0);
  stats_kernel<<<SB, 256, 0, stream>>>(AX, n, pstats);
  bnfin_kernel<<<1, 128, 0, stream>>>(pstats, g1, be1, bnp1, (float)n);

  // ---- layer 2 (fp16 in, BN1+lrelu fused) ----
  mmfma_kernel<1><<<MMB, 256, 0, stream>>>(AX, bnp1, Wp + 1 * 32768, rs_out, nullptr, nullptr, T1, n);
  agg_kernel<<<AGB, 256, 0, stream>>>(T1, row_ptr, csr_src, rs_in, b2, A2, n, 0);
  stats_kernel<<<SB, 256, 0, stream>>>(A2, n, pstats);
  bnfin_kernel<<<1, 128, 0, stream>>>(pstats, g2, be2, bnp2, (float)n);

  // ---- layer 3 (fp16 in, BN2 fused) ----
  mmfma_kernel<1><<<MMB, 256, 0, stream>>>(A2, bnp2, Wp + 2 * 32768, rs_out, nullptr, nullptr, T1, n);
  agg_kernel<<<AGB, 256, 0, stream>>>(T1, row_ptr, csr_src, rs_in, bn1, AX, n, 1);

  // ---- layer 4 (fp16 in, plain) ----
  mmfma_kernel<2><<<MMB, 256, 0, stream>>>(AX, nullptr, Wp + 3 * 32768, rs_out, nullptr, nullptr, T1, n);
  agg_kernel<<<AGB, 256, 0, stream>>>(T1, row_ptr, csr_src, rs_in, bn2, AX, n, 1);

  // ---- node_out ----
  nodeout_kernel<<<NOB, 256, 0, stream>>>(AX, Wnc, bnc, (float*)d_out, n);

  // ---- layer 5 (fp16 in, BN2 fused; rank-1 fold of nodetype) ----
  mmfma_kernel<1><<<MMB, 256, 0, stream>>>(A2, bnp2, Wp + 4 * 32768, rs_out, nodetype, Wg1 + HD * HD, T1, n);
  agg_kernel<<<AGB, 256, 0, stream>>>(T1, row_ptr, csr_src, rs_in, bg1, AX, n, 1);

  // ---- graph mean (two-stage, no atomics) + graph_out ----
  gpart_kernel<<<64 * GK, 256, 0, stream>>>(AX, gid, partial, n);
  gfin_kernel<<<64, 128, 0, stream>>>(partial, gid, Wgc, bgc, (float*)d_out + (size_t)n * 8, n);
}

// Round 12
// 426.732 us; speedup vs baseline: 1.2350x; 1.1838x over previous
//
#include <hip/hip_runtime.h>
#include <cstdint>
#include <cstddef>

#define NN 50000
#define NE 800000
#define HD 128
#define GK 16     // chunk-blocks per graph in gpart
#define HNB 64    // edge-slice blocks per (array,half) in deghist
#define SB 256    // stats partial blocks

typedef __attribute__((ext_vector_type(8))) short bf16x8;
typedef __attribute__((ext_vector_type(4))) float f32x4;
typedef _Float16 f16x4 __attribute__((ext_vector_type(4)));
typedef _Float16 f16x8 __attribute__((ext_vector_type(8)));

__device__ inline unsigned short f2bf(float x) {
  unsigned u = __float_as_uint(x);
  u += 0x7FFF + ((u >> 16) & 1);  // round-to-nearest-even
  return (unsigned short)(u >> 16);
}
__device__ inline float bf2f(unsigned short h) { return __uint_as_float((unsigned)h << 16); }

// ---------------- degree histogram via LDS privatization (no global atomics) ----------------
__global__ __launch_bounds__(256) void deghist_kernel(const int* __restrict__ src, const int* __restrict__ dst,
                                                      int* __restrict__ part, int e) {
  __shared__ int hist[25000];  // 100 KB
  const int b = blockIdx.x >> 2;
  const int sel = (blockIdx.x >> 1) & 1;
  const int h = blockIdx.x & 1;
  const int* arr = sel ? dst : src;
  for (int i = threadIdx.x; i < 25000; i += 256) hist[i] = 0;
  __syncthreads();
  const int lo = h * 25000;
  const int slice = e >> 6;  // 12500
  const int base = b * slice;
  for (int i = base + threadIdx.x; i < base + slice; i += 256) {
    int v = arr[i] - lo;
    if ((unsigned)v < 25000u) atomicAdd(&hist[v], 1);  // LDS atomic: CU-local
  }
  __syncthreads();
  int* out = part + ((size_t)(sel * 2 + h) * HNB + b) * 25000;
  for (int i = threadIdx.x; i < 25000; i += 256) out[i] = hist[i];
}

// ---------------- fused: degree reduce + rs factors + block-level exclusive scan ----------------
__global__ __launch_bounds__(256) void degscan_kernel(const int* __restrict__ part, int* __restrict__ excl,
                                                      int* __restrict__ bsum, float* __restrict__ rs_out,
                                                      float* __restrict__ rs_in, int n) {
  int v = blockIdx.x * 256 + threadIdx.x;
  int is = 0;
  if (v < n) {
    const int h = (v >= 25000) ? 1 : 0;
    const int bin = v - h * 25000;
    const int* p0 = part + ((size_t)(0 + h) * HNB) * 25000 + bin;  // src -> out-deg
    const int* p1 = part + ((size_t)(2 + h) * HNB) * 25000 + bin;  // dst -> in-deg
    int os = 0;
#pragma unroll 8
    for (int b = 0; b < HNB; b++) {
      os += p0[(size_t)b * 25000];
      is += p1[(size_t)b * 25000];
    }
    rs_out[v] = rsqrtf((float)(os > 1 ? os : 1));
    rs_in[v] = rsqrtf((float)(is > 1 ? is : 1));
  }
  __shared__ int sh[256];
  sh[threadIdx.x] = is;
  __syncthreads();
  for (int off = 1; off < 256; off <<= 1) {
    int x = (threadIdx.x >= off) ? sh[threadIdx.x - off] : 0;
    __syncthreads();
    sh[threadIdx.x] += x;
    __syncthreads();
  }
  if (v < n) excl[v] = sh[threadIdx.x] - is;
  if (threadIdx.x == 255) bsum[blockIdx.x] = sh[255];
}

// ---------------- scan finalize: inline serial prefix of bsum (<=196 iters) ----------------
__global__ __launch_bounds__(256) void scan3_kernel(const int* __restrict__ excl, const int* __restrict__ bsum,
                                                    int* __restrict__ row_ptr, int n, int e) {
  int base = 0;
  for (int b = 0; b < blockIdx.x; b++) base += bsum[b];  // scalar-cached, uniform
  int i = blockIdx.x * 256 + threadIdx.x;
  if (i < n) row_ptr[i] = excl[i] + base;
  if (i == 0) row_ptr[n] = e;
}

// ---------------- per-(slice,half) start offsets ----------------
__global__ __launch_bounds__(256) void scanoffs_kernel(const int* __restrict__ part, const int* __restrict__ row_ptr,
                                                       int* __restrict__ offs, int n) {
  int v = blockIdx.x * 256 + threadIdx.x;
  if (v >= n) return;
  const int h = (v >= 25000) ? 1 : 0;
  const int bin = v - h * 25000;
  const int* p = part + ((size_t)(2 + h) * HNB) * 25000 + bin;  // dst partials
  int run = row_ptr[v];
#pragma unroll 8
  for (int b = 0; b < HNB; b++) {
    offs[((size_t)(b * 2 + h)) * 25000 + bin] = run;
    run += p[(size_t)b * 25000];
  }
}

// ---------------- CSR fill with LDS cursors (no global atomics) ----------------
__global__ __launch_bounds__(256) void fill2_kernel(const int* __restrict__ src, const int* __restrict__ dst,
                                                    const int* __restrict__ offs, int* __restrict__ csr_src, int e) {
  __shared__ int cur[25000];  // 100 KB
  const int b = blockIdx.x >> 1;
  const int h = blockIdx.x & 1;
  const int* o = offs + ((size_t)(b * 2 + h)) * 25000;
  for (int i = threadIdx.x; i < 25000; i += 256) cur[i] = o[i];
  __syncthreads();
  const int lo = h * 25000;
  const int slice = e >> 6;  // 12500
  const int base = b * slice;
  for (int i = base + threadIdx.x; i < base + slice; i += 256) {
    int v = dst[i] - lo;
    if ((unsigned)v < 25000u) {
      int pos = atomicAdd(&cur[v], 1);  // LDS atomic: CU-local
      csr_src[pos] = src[i];
    }
  }
}

// ---------------- weight pack: f32 [128][128] -> hi/lo bf16 in MFMA B-fragment order ----------------
__global__ __launch_bounds__(256) void convw_kernel(const float* __restrict__ W1, const float* __restrict__ W2,
                                                    const float* __restrict__ Wn1, const float* __restrict__ Wn2,
                                                    const float* __restrict__ Wg1, unsigned short* __restrict__ Wp) {
  const float* Ws[5] = {W1, W2, Wn1, Wn2, Wg1};
  const float* W = Ws[blockIdx.x];
  unsigned short* hi = Wp + (size_t)blockIdx.x * 32768;
  unsigned short* lo = hi + 16384;
  for (int s = threadIdx.x; s < 2048; s += 256) {
    int f = s >> 6, lane = s & 63;
    int ct = f >> 2, ks = f & 3;
    int col = ct * 16 + (lane & 15);
    int k0 = ks * 32 + ((lane >> 4) << 3);
    for (int j = 0; j < 8; j++) {
      float v = W[(k0 + j) * HD + col];
      unsigned short h = f2bf(v);
      hi[s * 8 + j] = h;
      lo[s * 8 + j] = f2bf(v - bf2f(h));
    }
  }
}

// ---------------- MFMA GEMM with fused input transform; fp16 output (16 rows/wave, R9 config) ----------------
// MODE 0: A is f32, no BN (layer 1).  MODE 1: A is fp16, BN+lrelu fused.  MODE 2: A is fp16, plain.
template <int MODE>
__global__ __launch_bounds__(256) void mmfma_kernel(const void* __restrict__ Ain,
                                                    const float* __restrict__ bnp,
                                                    const unsigned short* __restrict__ Wp,
                                                    const float* __restrict__ rs,
                                                    const float* __restrict__ evec,
                                                    const float* __restrict__ erow,
                                                    _Float16* __restrict__ C, int n) {
  const int lane = threadIdx.x & 63;
  const int wv = threadIdx.x >> 6;
  const int rbase = (blockIdx.x * 4 + wv) * 16;
  if (rbase >= n) return;
  const int rA = min(rbase + (lane & 15), n - 1);
  const int koff = (lane >> 4) << 3;
  const unsigned short* wlo = Wp + 16384;
  f32x4 acc[8];
#pragma unroll
  for (int t = 0; t < 8; t++) acc[t] = (f32x4){0.f, 0.f, 0.f, 0.f};
#pragma unroll
  for (int ks = 0; ks < 4; ks++) {
    const int c0 = ks * 32 + koff;
    float av[8];
    if (MODE == 0) {
      const float* ap = (const float*)Ain + (size_t)rA * HD + c0;
      float4 a0 = *reinterpret_cast<const float4*>(ap);
      float4 a1 = *reinterpret_cast<const float4*>(ap + 4);
      av[0] = a0.x; av[1] = a0.y; av[2] = a0.z; av[3] = a0.w;
      av[4] = a1.x; av[5] = a1.y; av[6] = a1.z; av[7] = a1.w;
    } else {
      const _Float16* ap = (const _Float16*)Ain + (size_t)rA * HD + c0;
      f16x8 a = *reinterpret_cast<const f16x8*>(ap);
#pragma unroll
      for (int j = 0; j < 8; j++) av[j] = (float)a[j];
    }
    if (MODE == 1) {
#pragma unroll
      for (int j = 0; j < 8; j++) {
        float x = fmaf(av[j], bnp[c0 + j], bnp[128 + c0 + j]);
        av[j] = x >= 0.f ? x : 0.01f * x;
      }
    }
    bf16x8 ah, al;
#pragma unroll
    for (int j = 0; j < 8; j++) {
      unsigned short hh = f2bf(av[j]);
      ((short*)&ah)[j] = (short)hh;
      ((short*)&al)[j] = (short)f2bf(av[j] - bf2f(hh));
    }
#pragma unroll
    for (int ct = 0; ct < 8; ct++) {
      int fo = ((ct * 4 + ks) * 64 + lane) * 8;
      bf16x8 bh = *reinterpret_cast<const bf16x8*>(Wp + fo);
      bf16x8 bl = *reinterpret_cast<const bf16x8*>(wlo + fo);
      acc[ct] = __builtin_amdgcn_mfma_f32_16x16x32_bf16(ah, bh, acc[ct], 0, 0, 0);
      acc[ct] = __builtin_amdgcn_mfma_f32_16x16x32_bf16(al, bh, acc[ct], 0, 0, 0);
      acc[ct] = __builtin_amdgcn_mfma_f32_16x16x32_bf16(ah, bl, acc[ct], 0, 0, 0);
    }
  }
  const int r0 = rbase + ((lane >> 4) << 2);
  const int cbase = lane & 15;
#pragma unroll
  for (int i = 0; i < 4; i++) {
    int r = r0 + i;
    if (r < n) {
      float rsv = rs[r];
      float ev = (evec != nullptr) ? evec[r] : 0.f;
      _Float16* crow = C + (size_t)r * HD + cbase;
#pragma unroll
      for (int ct = 0; ct < 8; ct++) {
        float v = acc[ct][i];
        if (evec != nullptr) v = fmaf(ev, erow[ct * 16 + cbase], v);
        crow[ct * 16] = (_Float16)(v * rsv);
      }
    }
  }
}

// ---------------- pull-mode aggregation: wave = node, 2 edges/load, fp16 in AND out (R9 config) ----------------
__global__ __launch_bounds__(256) void agg_kernel(const _Float16* __restrict__ Ys, const int* __restrict__ row_ptr,
                                                  const int* __restrict__ csr_src, const float* __restrict__ rs_in,
                                                  const float* __restrict__ bias, _Float16* __restrict__ out,
                                                  int n, int do_lrelu) {
  const int wave = threadIdx.x >> 6;
  const int lane = threadIdx.x & 63;
  const int half = lane >> 5;
  const int li = lane & 31;
  const int node = blockIdx.x * 4 + wave;
  if (node >= n) return;
  const int beg = row_ptr[node], end = row_ptr[node + 1];
  const int cnt = end - beg;
  const int npairs = cnt >> 1;
  float a0 = 0.f, a1 = 0.f, a2 = 0.f, a3 = 0.f;
  int p = 0;
  for (; p + 8 <= npairs; p += 8) {
    int s[8];
#pragma unroll
    for (int j = 0; j < 8; j++) s[j] = csr_src[beg + 2 * (p + j) + half];
    f16x4 v[8];
#pragma unroll
    for (int j = 0; j < 8; j++) v[j] = reinterpret_cast<const f16x4*>(Ys + (size_t)s[j] * HD)[li];
#pragma unroll
    for (int j = 0; j < 8; j++) {
      a0 += (float)v[j].x;
      a1 += (float)v[j].y;
      a2 += (float)v[j].z;
      a3 += (float)v[j].w;
    }
  }
  for (; p < npairs; ++p) {
    int s = csr_src[beg + 2 * p + half];
    f16x4 v = reinterpret_cast<const f16x4*>(Ys + (size_t)s * HD)[li];
    a0 += (float)v.x;
    a1 += (float)v.y;
    a2 += (float)v.z;
    a3 += (float)v.w;
  }
  if ((cnt & 1) && half == 0) {  // odd tail -> half 0 only
    int s = csr_src[end - 1];
    f16x4 v = reinterpret_cast<const f16x4*>(Ys + (size_t)s * HD)[li];
    a0 += (float)v.x;
    a1 += (float)v.y;
    a2 += (float)v.z;
    a3 += (float)v.w;
  }
  a0 += __shfl_xor(a0, 32, 64);
  a1 += __shfl_xor(a1, 32, 64);
  a2 += __shfl_xor(a2, 32, 64);
  a3 += __shfl_xor(a3, 32, 64);
  if (half == 0) {
    float ri = rs_in[node];
    float4 b = reinterpret_cast<const float4*>(bias)[li];
    float o0 = fmaf(a0, ri, b.x);
    float o1 = fmaf(a1, ri, b.y);
    float o2 = fmaf(a2, ri, b.z);
    float o3 = fmaf(a3, ri, b.w);
    if (do_lrelu) {
      o0 = o0 >= 0.f ? o0 : 0.01f * o0;
      o1 = o1 >= 0.f ? o1 : 0.01f * o1;
      o2 = o2 >= 0.f ? o2 : 0.01f * o2;
      o3 = o3 >= 0.f ? o3 : 0.01f * o3;
    }
    f16x4 ov = {(_Float16)o0, (_Float16)o1, (_Float16)o2, (_Float16)o3};
    reinterpret_cast<f16x4*>(out + (size_t)node * HD)[li] = ov;
  }
}

// ---------------- BN statistics: SB row-chunk blocks, f16x8 vector loads, LDS reduce ----------------
// thread (cg = t&15, ro = t>>4): columns cg*8..cg*8+7, rows r0+ro, r0+ro+16, ...
// wave reads 4 consecutive full rows = 1 KB contiguous per iteration.
__global__ __launch_bounds__(256) void stats_kernel(const _Float16* __restrict__ Z, int n,
                                                    float* __restrict__ pstats) {
  const int chunk = (n + SB - 1) / SB;  // 196
  const int r0 = blockIdx.x * chunk;
  const int r1 = min(r0 + chunk, n);
  const int cg = threadIdx.x & 15;
  const int ro = threadIdx.x >> 4;
  float s[8], s2[8];
#pragma unroll
  for (int j = 0; j < 8; j++) { s[j] = 0.f; s2[j] = 0.f; }
  for (int r = r0 + ro; r < r1; r += 16) {
    f16x8 v = *reinterpret_cast<const f16x8*>(Z + (size_t)r * HD + cg * 8);
#pragma unroll
    for (int j = 0; j < 8; j++) {
      float x = (float)v[j];
      s[j] += x;
      s2[j] = fmaf(x, x, s2[j]);
    }
  }
  __shared__ float lsum[16][16][8];  // [ro][cg][j], 8 KB
  __shared__ float lsq[16][16][8];
#pragma unroll
  for (int j = 0; j < 8; j++) {
    lsum[ro][cg][j] = s[j];
    lsq[ro][cg][j] = s2[j];
  }
  __syncthreads();
  if (threadIdx.x < 128) {
    int cg2 = threadIdx.x >> 3, j2 = threadIdx.x & 7;
    float a = 0.f, b = 0.f;
#pragma unroll
    for (int t = 0; t < 16; t++) {
      a += lsum[t][cg2][j2];
      b += lsq[t][cg2][j2];
    }
    pstats[(size_t)blockIdx.x * 256 + cg2 * 8 + j2] = a;
    pstats[(size_t)blockIdx.x * 256 + 128 + cg2 * 8 + j2] = b;
  }
}

__global__ void bnfin_kernel(const float* __restrict__ pstats, const float* __restrict__ gamma,
                             const float* __restrict__ beta, float* __restrict__ bnp, float n) {
  int c = threadIdx.x;  // 128
  float s = 0.f, s2 = 0.f;
  for (int j = 0; j < SB; j++) {
    s += pstats[(size_t)j * 256 + c];
    s2 += pstats[(size_t)j * 256 + 128 + c];
  }
  float mu = s / n;
  float var = s2 / n - mu * mu;
  if (var < 0.f) var = 0.f;
  float sc = gamma[c] * rsqrtf(var + 1e-5f);
  bnp[c] = sc;
  bnp[128 + c] = fmaf(-mu, sc, beta[c]);
}

// ---------------- node_out = X@Wnc + b_nc  ([n,128]@[128,8], fp16 X) ----------------
__global__ __launch_bounds__(256) void nodeout_kernel(const _Float16* __restrict__ X, const float* __restrict__ Wnc,
                                                      const float* __restrict__ b, float* __restrict__ out, int n) {
  __shared__ float Wl[HD * 8];
  __shared__ float bl[8];
  for (int i = threadIdx.x; i < HD * 8; i += 256) Wl[i] = Wnc[i];
  if (threadIdx.x < 8) bl[threadIdx.x] = b[threadIdx.x];
  __syncthreads();
  int t = blockIdx.x * 256 + threadIdx.x;
  int r = t >> 3, c = t & 7;
  if (r >= n) return;
  const _Float16* x = X + (size_t)r * HD;
  float acc = bl[c];
  for (int k = 0; k < HD; k += 4) {
    f16x4 a = *reinterpret_cast<const f16x4*>(x + k);
    acc = fmaf((float)a.x, Wl[k * 8 + c], acc);
    acc = fmaf((float)a.y, Wl[(k + 1) * 8 + c], acc);
    acc = fmaf((float)a.z, Wl[(k + 2) * 8 + c], acc);
    acc = fmaf((float)a.w, Wl[(k + 3) * 8 + c], acc);
  }
  out[(size_t)r * 8 + c] = acc;
}

// ---------------- graph mean stage 1: 64 graphs x GK chunk-blocks, fp16 input ----------------
__global__ __launch_bounds__(256) void gpart_kernel(const _Float16* __restrict__ HG, const int* __restrict__ gid,
                                                    float* __restrict__ partial, int n) {
  const int g = blockIdx.x >> 4;  // GK==16
  const int j = blockIdx.x & 15;
  int lo = 0, hi = n;
  while (lo < hi) { int mid = (lo + hi) >> 1; if (gid[mid] < g) lo = mid + 1; else hi = mid; }
  const int beg = lo;
  lo = 0; hi = n;
  while (lo < hi) { int mid = (lo + hi) >> 1; if (gid[mid] < g + 1) lo = mid + 1; else hi = mid; }
  const int end = lo;
  const int len = end - beg;
  const int chunk = (len + GK - 1) / GK;
  const int r0 = beg + j * chunk;
  const int r1 = min(r0 + chunk, end);

  const int c = threadIdx.x & 127;
  const int half = threadIdx.x >> 7;
  float s = 0.f;
  for (int r = r0 + half; r < r1; r += 2)
    s += (float)HG[(size_t)r * HD + c];

  __shared__ float sh[256];
  sh[threadIdx.x] = s;
  __syncthreads();
  if (threadIdx.x < 128)
    partial[(size_t)blockIdx.x * HD + threadIdx.x] = sh[threadIdx.x] + sh[threadIdx.x + 128];
}

// ---------------- graph mean stage 2: reduce GK partials, scale, @Wgc + bgc ----------------
__global__ __launch_bounds__(128) void gfin_kernel(const float* __restrict__ partial, const int* __restrict__ gid,
                                                   const float* __restrict__ Wgc, const float* __restrict__ bgc,
                                                   float* __restrict__ out, int n) {
  const int g = blockIdx.x;
  int lo = 0, hi = n;
  while (lo < hi) { int mid = (lo + hi) >> 1; if (gid[mid] < g) lo = mid + 1; else hi = mid; }
  const int beg = lo;
  lo = 0; hi = n;
  while (lo < hi) { int mid = (lo + hi) >> 1; if (gid[mid] < g + 1) lo = mid + 1; else hi = mid; }
  const int end = lo;
  float cntf = (float)(end - beg);
  float inv = 1.f / (cntf > 1.f ? cntf : 1.f);

  const int c = threadIdx.x;  // 128
  float s = 0.f;
#pragma unroll
  for (int j = 0; j < GK; j++) s += partial[(size_t)(g * GK + j) * HD + c];
  __shared__ float sh[128];
  sh[c] = s * inv;
  __syncthreads();
  if (c < 4) {
    float acc = bgc[c];
    for (int k = 0; k < HD; k++) acc = fmaf(sh[k], Wgc[k * 4 + c], acc);
    out[g * 4 + c] = acc;
  }
}

extern "C" void kernel_launch(void* const* d_in, const int* in_sizes, int n_in,
                              void* d_out, int out_size, void* d_ws, size_t ws_size,
                              hipStream_t stream) {
  const float* node_feat = (const float*)d_in[0];
  const float* nodetype = (const float*)d_in[1];
  // d_in[2] edge_feat: dead branch, unused
  const float* W1 = (const float*)d_in[3];
  const float* b1 = (const float*)d_in[4];
  const float* g1 = (const float*)d_in[5];
  const float* be1 = (const float*)d_in[6];
  const float* W2 = (const float*)d_in[7];
  const float* b2 = (const float*)d_in[8];
  const float* g2 = (const float*)d_in[9];
  const float* be2 = (const float*)d_in[10];
  // 11 We, 12 b_e: dead
  const float* Wn1 = (const float*)d_in[13];
  const float* bn1 = (const float*)d_in[14];
  const float* Wn2 = (const float*)d_in[15];
  const float* bn2 = (const float*)d_in[16];
  const float* Wnc = (const float*)d_in[17];
  const float* bnc = (const float*)d_in[18];
  const float* Wg1 = (const float*)d_in[19];
  const float* bg1 = (const float*)d_in[20];
  const float* Wgc = (const float*)d_in[21];
  const float* bgc = (const float*)d_in[22];
  const int* src = (const int*)d_in[23];
  const int* dst = (const int*)d_in[24];
  const int* gid = (const int*)d_in[25];

  const int n = NN, e = NE;

  // ---- workspace carve (256B aligned) ----
  char* w = (char*)d_ws;
  auto alloc = [&](size_t bytes) -> void* {
    void* p = (void*)w;
    w += (bytes + 255) & ~(size_t)255;
    return p;
  };
  _Float16* T1 = (_Float16*)alloc((size_t)n * HD * 4);  // fp16 mm out (half used); aliases deghist partials (25.6 MB)
  _Float16* AX = (_Float16*)alloc((size_t)n * HD * 2);  // fp16 agg out L1/L3/L4/L5 (disjoint live ranges)
  _Float16* A2 = (_Float16*)alloc((size_t)n * HD * 2);  // fp16 agg out L2; prologue aliases fill offsets (12.8 MB)
  int* hpart = (int*)T1;                                // 4*HNB*25000*4 B = 25.6 MB
  int* offs = (int*)A2;                                 // 2*HNB*25000*4 B = 12.8 MB; dead before L2 agg
  int* csr_src = (int*)alloc((size_t)e * 4);
  int* row_ptr = (int*)alloc((size_t)(n + 1) * 4);
  int* excl = (int*)alloc((size_t)n * 4);
  int* bsum = (int*)alloc(256 * 4);
  float* rs_out = (float*)alloc((size_t)n * 4);
  float* rs_in = (float*)alloc((size_t)n * 4);
  float* pstats = (float*)alloc((size_t)SB * 256 * 4);
  float* bnp1 = (float*)alloc(256 * 4);
  float* bnp2 = (float*)alloc(256 * 4);
  unsigned short* Wp = (unsigned short*)alloc(5 * 32768 * 2);
  float* partial = (float*)alloc((size_t)64 * GK * HD * 4);

  const int NB = (n + 255) / 256;
  const int MMB = (n + 63) / 64;  // 782: 4 waves x 16 rows (R9 config)
  const int AGB = (n + 3) / 4;
  const int NOB = (n * 8 + 255) / 256;

  // ---- weight pack ----
  convw_kernel<<<5, 256, 0, stream>>>(W1, W2, Wn1, Wn2, Wg1, Wp);

  // ---- degrees + CSR build (fully atomic-free on global memory) ----
  deghist_kernel<<<HNB * 4, 256, 0, stream>>>(src, dst, hpart, e);
  degscan_kernel<<<NB, 256, 0, stream>>>(hpart, excl, bsum, rs_out, rs_in, n);
  scan3_kernel<<<NB, 256, 0, stream>>>(excl, bsum, row_ptr, n, e);
  scanoffs_kernel<<<NB, 256, 0, stream>>>(hpart, row_ptr, offs, n);
  fill2_kernel<<<HNB * 2, 256, 0, stream>>>(src, dst, offs, csr_src, e);

  // ---- layer 1 (f32 node_feat in) ----
  mmfma_kernel<0><<<MMB, 256, 0, stream>>>(node_feat, nullptr, Wp + 0 * 32768, rs_out, nullptr, nullptr, T1, n);
  agg_kernel<<<AGB, 256, 0, stream>>>(T1, row_ptr, csr_src, rs_in, b1, AX, n, 0);
  stats_kernel<<<SB, 256, 0, stream>>>(AX, n, pstats);
  bnfin_kernel<<<1, 128, 0, stream>>>(pstats, g1, be1, bnp1, (float)n);

  // ---- layer 2 (fp16 in, BN1+lrelu fused) ----
  mmfma_kernel<1><<<MMB, 256, 0, stream>>>(AX, bnp1, Wp + 1 * 32768, rs_out, nullptr, nullptr, T1, n);
  agg_kernel<<<AGB, 256, 0, stream>>>(T1, row_ptr, csr_src, rs_in, b2, A2, n, 0);
  stats_kernel<<<SB, 256, 0, stream>>>(A2, n, pstats);
  bnfin_kernel<<<1, 128, 0, stream>>>(pstats, g2, be2, bnp2, (float)n);

  // ---- layer 3 (fp16 in, BN2 fused) ----
  mmfma_kernel<1><<<MMB, 256, 0, stream>>>(A2, bnp2, Wp + 2 * 32768, rs_out, nullptr, nullptr, T1, n);
  agg_kernel<<<AGB, 256, 0, stream>>>(T1, row_ptr, csr_src, rs_in, bn1, AX, n, 1);

  // ---- layer 4 (fp16 in, plain) ----
  mmfma_kernel<2><<<MMB, 256, 0, stream>>>(AX, nullptr, Wp + 3 * 32768, rs_out, nullptr, nullptr, T1, n);
  agg_kernel<<<AGB, 256, 0, stream>>>(T1, row_ptr, csr_src, rs_in, bn2, AX, n, 1);

  // ---- node_out ----
  nodeout_kernel<<<NOB, 256, 0, stream>>>(AX, Wnc, bnc, (float*)d_out, n);

  // ---- layer 5 (fp16 in, BN2 fused; rank-1 fold of nodetype) ----
  mmfma_kernel<1><<<MMB, 256, 0, stream>>>(A2, bnp2, Wp + 4 * 32768, rs_out, nodetype, Wg1 + HD * HD, T1, n);
  agg_kernel<<<AGB, 256, 0, stream>>>(T1, row_ptr, csr_src, rs_in, bg1, AX, n, 1);

  // ---- graph mean (two-stage, no atomics) + graph_out ----
  gpart_kernel<<<64 * GK, 256, 0, stream>>>(AX, gid, partial, n);
  gfin_kernel<<<64, 128, 0, stream>>>(partial, gid, Wgc, bgc, (float*)d_out + (size_t)n * 8, n);
}